// Round 3
// baseline (687.469 us; speedup 1.0000x reference)
//
#include <hip/hip_runtime.h>
#include <hip/hip_bf16.h>

// GCN 2-layer: x[100k,128] @ W1 -> norm-agg -> +b1 -> sigmoid -> @ W2 -> norm-agg -> +b2 -> log_softmax
// Dtypes are detected at RUNTIME (device-side) because the dataset may be
// fp32-or-bf16 for floats and int32-or-int64 for edge_index:
//   flags[0] = 1 if float arrays are bf16, 0 if fp32
//   flags[1] = 1 if edge_index is int64, 0 if int32
// All internal compute is fp32.

constexpr int D_IN  = 128;
constexpr int D_HID = 64;
constexpr int D_OUT = 16;

__device__ inline float bflo(unsigned u){ return __uint_as_float(u << 16); }
__device__ inline float bfhi(unsigned u){ return __uint_as_float(u & 0xffff0000u); }
__device__ inline float sigf(float x){ return 1.0f / (1.0f + __expf(-x)); }

// ---------------- dtype detection ----------------
__global__ void k_detect(const unsigned* __restrict__ xraw,
                         const int* __restrict__ eraw,
                         int* __restrict__ flags)
{
    if (blockIdx.x == 0 && threadIdx.x == 0){
        // floats: bf16 iff interpreting words as bf16 PAIRS gives sane exponents
        int bad = 0;
        for (int i = 0; i < 64; ++i){
            unsigned w = xraw[i];
            unsigned h0 = w & 0xffffu, h1 = w >> 16;
            unsigned e0 = (h0 >> 7) & 0xffu, e1 = (h1 >> 7) & 0xffu;
            if (!((h0 & 0x7fffu) == 0 || (e0 >= 97 && e0 <= 157))) ++bad;
            if (!((h1 & 0x7fffu) == 0 || (e1 >= 97 && e1 <= 157))) ++bad;
        }
        flags[0] = (bad > 8) ? 0 : 1;
        // ints: int64 iff odd int32 words are ~all zero (ids < 2^31)
        int zeroOdd = 0;
        for (int i = 0; i < 64; ++i)
            if (eraw[2 * i + 1] == 0) ++zeroOdd;
        flags[1] = (zeroOdd > 48) ? 1 : 0;
    }
}

__device__ inline int edge_src(const int* ei, int e, int /*ne*/, int i64){
    return i64 ? ei[2 * e] : ei[e];
}
__device__ inline int edge_dst(const int* ei, int e, int ne, int i64){
    return i64 ? ei[2 * (ne + e)] : ei[ne + e];
}

// ---------------- degree / dinv ----------------
__global__ void k_deg_init(float* __restrict__ deg, int n){
    int i = blockIdx.x * 256 + threadIdx.x;
    if (i < n) deg[i] = 1.0f;               // self loop
}

__global__ void k_deg_count(const int* __restrict__ ei, const int* __restrict__ flags,
                            float* __restrict__ deg, int ne){
    int e = blockIdx.x * 256 + threadIdx.x;
    int i64 = flags[1];
    if (e < ne) atomicAdd(&deg[edge_dst(ei, e, ne, i64)], 1.0f);
}

__global__ void k_dinv(float* __restrict__ deg, int n){
    int i = blockIdx.x * 256 + threadIdx.x;
    if (i < n) deg[i] = rsqrtf(deg[i]);     // deg >= 1 always
}

// ---------------- linear 1: h1 = x @ W1 ; agg1 = h1 * dinv^2 (self-loop seed) ----------------
__global__ __launch_bounds__(256) void k_linear1(
    const unsigned* __restrict__ xraw, const unsigned* __restrict__ w1raw,
    const int* __restrict__ flags,
    const float* __restrict__ dinv, float* __restrict__ h1, float* __restrict__ agg1, int n)
{
    __shared__ float w1s[D_IN * D_HID];     // 32 KB fp32
    __shared__ float xs[16][132];           // pad 132 -> conflict-free broadcast

    const int isBf16 = flags[0];

    if (isBf16){
        const uint4* wv = (const uint4*)w1raw;
        for (int i = threadIdx.x; i < (D_IN * D_HID) / 8; i += 256){
            uint4 u = wv[i];
            float* o = &w1s[i * 8];
            o[0]=bflo(u.x); o[1]=bfhi(u.x); o[2]=bflo(u.y); o[3]=bfhi(u.y);
            o[4]=bflo(u.z); o[5]=bfhi(u.z); o[6]=bflo(u.w); o[7]=bfhi(u.w);
        }
    } else {
        const float4* wv = (const float4*)w1raw;
        for (int i = threadIdx.x; i < (D_IN * D_HID) / 4; i += 256)
            ((float4*)w1s)[i] = wv[i];
    }

    const int ln = threadIdx.x >> 4;        // node-local 0..15
    const int cg = threadIdx.x & 15;        // col group: cols 4*cg..4*cg+3

    for (int nb = blockIdx.x * 16; nb < n; nb += gridDim.x * 16){
        {   // stage 16 x rows as fp32
            int node = nb + ln;
            float4 a, b;
            if (node >= n){
                a = make_float4(0,0,0,0); b = a;
            } else if (isBf16){
                uint4 u = ((const uint4*)xraw)[(size_t)node * (D_IN / 8) + cg];
                a = make_float4(bflo(u.x), bfhi(u.x), bflo(u.y), bfhi(u.y));
                b = make_float4(bflo(u.z), bfhi(u.z), bflo(u.w), bfhi(u.w));
            } else {
                const float4* xr = (const float4*)xraw;
                a = xr[(size_t)node * (D_IN / 4) + cg * 2];
                b = xr[(size_t)node * (D_IN / 4) + cg * 2 + 1];
            }
            float4* o = (float4*)&xs[ln][cg * 8];
            o[0] = a; o[1] = b;
        }
        __syncthreads();

        int node = nb + ln;
        float a0=0.f, a1=0.f, a2=0.f, a3=0.f;
        #pragma unroll 8
        for (int k = 0; k < D_IN; ++k){
            float xv = xs[ln][k];                       // broadcast within node group
            const float* wr = &w1s[k * D_HID + cg * 4]; // ds_read_b128
            a0 = fmaf(xv, wr[0], a0);
            a1 = fmaf(xv, wr[1], a1);
            a2 = fmaf(xv, wr[2], a2);
            a3 = fmaf(xv, wr[3], a3);
        }
        if (node < n){
            float di = dinv[node];
            float sl = di * di;
            size_t off = (size_t)node * D_HID + cg * 4;
            *(float4*)&h1[off]   = make_float4(a0, a1, a2, a3);
            *(float4*)&agg1[off] = make_float4(a0*sl, a1*sl, a2*sl, a3*sl);
        }
        __syncthreads();
    }
}

// ---------------- edge aggregation, layer 1 (wave per edge, lane = feature) ----------------
__global__ __launch_bounds__(256) void k_agg1(
    const int* __restrict__ ei, const int* __restrict__ flags,
    const float* __restrict__ dinv, const float* __restrict__ h1,
    float* __restrict__ agg1, int ne)
{
    int gid = blockIdx.x * 256 + threadIdx.x;
    int e = gid >> 6, lane = gid & 63;
    int i64 = flags[1];
    if (e < ne){
        int s = edge_src(ei, e, ne, i64);
        int d = edge_dst(ei, e, ne, i64);
        float w = dinv[s] * dinv[d];
        float v = h1[(size_t)s * D_HID + lane] * w;
        atomicAdd(&agg1[(size_t)d * D_HID + lane], v);
    }
}

// ---------------- activation: a = sigmoid(a + b1) in place ----------------
__global__ void k_act1(float* __restrict__ a, const unsigned* __restrict__ b1raw,
                       const int* __restrict__ flags, int total4){
    int i = blockIdx.x * 256 + threadIdx.x;
    int isBf16 = flags[0];
    if (i < total4){
        float4 v = ((float4*)a)[i];
        int c = (i & 15) * 4;   // row = 64 floats = 16 float4 chunks
        float b0, b1v, b2v, b3;
        if (isBf16){
            const __hip_bfloat16* b = (const __hip_bfloat16*)b1raw;
            b0 = __bfloat162float(b[c+0]); b1v = __bfloat162float(b[c+1]);
            b2v = __bfloat162float(b[c+2]); b3 = __bfloat162float(b[c+3]);
        } else {
            const float* b = (const float*)b1raw;
            b0 = b[c+0]; b1v = b[c+1]; b2v = b[c+2]; b3 = b[c+3];
        }
        v.x = sigf(v.x + b0); v.y = sigf(v.y + b1v);
        v.z = sigf(v.z + b2v); v.w = sigf(v.w + b3);
        ((float4*)a)[i] = v;
    }
}

// ---------------- linear 2: h2 = act @ W2 ; agg2 = h2 * dinv^2 ----------------
__global__ __launch_bounds__(256) void k_linear2(
    const float* __restrict__ act, const unsigned* __restrict__ w2raw,
    const int* __restrict__ flags,
    const float* __restrict__ dinv, float* __restrict__ h2, float* __restrict__ agg2, int n)
{
    __shared__ float w2s[D_HID * D_OUT];    // 4 KB
    __shared__ float as[16][68];

    const int isBf16 = flags[0];

    if (isBf16){
        const uint4* wv = (const uint4*)w2raw;
        for (int i = threadIdx.x; i < (D_HID * D_OUT) / 8; i += 256){
            uint4 u = wv[i];
            float* o = &w2s[i * 8];
            o[0]=bflo(u.x); o[1]=bfhi(u.x); o[2]=bflo(u.y); o[3]=bfhi(u.y);
            o[4]=bflo(u.z); o[5]=bfhi(u.z); o[6]=bflo(u.w); o[7]=bfhi(u.w);
        }
    } else {
        const float4* wv = (const float4*)w2raw;
        for (int i = threadIdx.x; i < (D_HID * D_OUT) / 4; i += 256)
            ((float4*)w2s)[i] = wv[i];
    }

    const int ln  = threadIdx.x >> 4;       // node-local 0..15
    const int col = threadIdx.x & 15;       // output col

    for (int nb = blockIdx.x * 16; nb < n; nb += gridDim.x * 16){
        {
            int node = nb + ln;
            float4 v = (node < n) ? *(const float4*)&act[(size_t)node * D_HID + col * 4]
                                  : make_float4(0,0,0,0);
            *(float4*)&as[ln][col * 4] = v;
        }
        __syncthreads();

        int node = nb + ln;
        float acc = 0.f;
        #pragma unroll 8
        for (int k = 0; k < D_HID; ++k)
            acc = fmaf(as[ln][k], w2s[k * D_OUT + col], acc);

        if (node < n){
            float di = dinv[node];
            h2  [(size_t)node * D_OUT + col] = acc;
            agg2[(size_t)node * D_OUT + col] = acc * di * di;
        }
        __syncthreads();
    }
}

// ---------------- edge aggregation, layer 2 (16 lanes per edge) ----------------
__global__ __launch_bounds__(256) void k_agg2(
    const int* __restrict__ ei, const int* __restrict__ flags,
    const float* __restrict__ dinv, const float* __restrict__ h2,
    float* __restrict__ agg2, int ne)
{
    int gid = blockIdx.x * 256 + threadIdx.x;
    int e = gid >> 4, j = gid & 15;
    int i64 = flags[1];
    if (e < ne){
        int s = edge_src(ei, e, ne, i64);
        int d = edge_dst(ei, e, ne, i64);
        float w = dinv[s] * dinv[d];
        float v = h2[(size_t)s * D_OUT + j] * w;
        atomicAdd(&agg2[(size_t)d * D_OUT + j], v);
    }
}

// ---------------- epilogue: log_softmax over 16 cols, dtype-branched store ----------------
__global__ __launch_bounds__(256) void k_lsm(
    const float* __restrict__ agg2, const unsigned* __restrict__ b2raw,
    const int* __restrict__ flags, void* __restrict__ out, int n)
{
    int gid = blockIdx.x * 256 + threadIdx.x;
    int node = gid >> 4, j = gid & 15;
    int isBf16 = flags[0];
    if (node >= n) return;
    float bj = isBf16 ? __bfloat162float(((const __hip_bfloat16*)b2raw)[j])
                      : ((const float*)b2raw)[j];
    float v = agg2[(size_t)node * D_OUT + j] + bj;
    float m = v;
    #pragma unroll
    for (int off = 8; off; off >>= 1) m = fmaxf(m, __shfl_xor(m, off, 16));
    float e = __expf(v - m);
    float s = e;
    #pragma unroll
    for (int off = 8; off; off >>= 1) s += __shfl_xor(s, off, 16);
    float r = v - m - __logf(s);
    if (isBf16) ((__hip_bfloat16*)out)[(size_t)node * D_OUT + j] = __float2bfloat16(r);
    else        ((float*)out)[(size_t)node * D_OUT + j] = r;
}

extern "C" void kernel_launch(void* const* d_in, const int* in_sizes, int n_in,
                              void* d_out, int out_size, void* d_ws, size_t ws_size,
                              hipStream_t stream)
{
    const unsigned* xraw  = (const unsigned*)d_in[0];
    const int*      ei    = (const int*)d_in[1];
    const unsigned* w1raw = (const unsigned*)d_in[2];
    const unsigned* b1raw = (const unsigned*)d_in[3];
    const unsigned* w2raw = (const unsigned*)d_in[4];
    const unsigned* b2raw = (const unsigned*)d_in[5];

    const int n  = in_sizes[0] / D_IN;   // 100000
    const int ne = in_sizes[1] / 2;      // 1600000

    // ws layout (fp32 words): flags[64] | dinv[nAl] | bufA[n*64] | bufB[n*64]
    int*   flags = (int*)d_ws;
    float* dinv  = (float*)d_ws + 64;
    size_t nAl   = ((size_t)n + 63) & ~(size_t)63;
    float* bufA  = dinv + nAl;
    float* bufB  = bufA + (size_t)n * D_HID;
    float* h2    = bufA;                          // h1 dead after k_agg1
    float* agg2  = bufA + (size_t)n * D_OUT;

    k_detect   <<<1, 64, 0, stream>>>(xraw, ei, flags);

    k_deg_init <<<(n + 255) / 256, 256, 0, stream>>>(dinv, n);
    k_deg_count<<<(ne + 255) / 256, 256, 0, stream>>>(ei, flags, dinv, ne);
    k_dinv     <<<(n + 255) / 256, 256, 0, stream>>>(dinv, n);

    k_linear1  <<<768, 256, 0, stream>>>(xraw, w1raw, flags, dinv, bufA, bufB, n);
    k_agg1     <<<(ne + 3) / 4, 256, 0, stream>>>(ei, flags, dinv, bufA, bufB, ne);

    int t4 = n * D_HID / 4;
    k_act1     <<<(t4 + 255) / 256, 256, 0, stream>>>(bufB, b1raw, flags, t4);

    k_linear2  <<<768, 256, 0, stream>>>(bufB, w2raw, flags, dinv, h2, agg2, n);
    k_agg2     <<<(ne + 15) / 16, 256, 0, stream>>>(ei, flags, dinv, h2, agg2, ne);

    k_lsm      <<<((size_t)n * D_OUT + 255) / 256, 256, 0, stream>>>(agg2, b2raw, flags, d_out, n);
}

// Round 4
// 453.955 us; speedup vs baseline: 1.5144x; 1.5144x over previous
//
#include <hip/hip_runtime.h>
#include <hip/hip_bf16.h>

// GCN 2-layer, CSR-based aggregation (no fp32 atomics in the hot path).
// Pipeline: detect dtypes -> in-degree histogram -> prefix scan -> CSR fill
//   -> linear1(h1) -> aggA(CSR gather + self-loop + bias + sigmoid -> act)
//   -> linear2(h2) -> aggB(CSR gather + self-loop + bias + log_softmax -> out)
// flags[0]=1 if floats are bf16 else fp32; flags[1]=1 if edge_index int64 else int32.
// All internal compute fp32.

constexpr int D_IN  = 128;
constexpr int D_HID = 64;
constexpr int D_OUT = 16;

__device__ inline float bflo(unsigned u){ return __uint_as_float(u << 16); }
__device__ inline float bfhi(unsigned u){ return __uint_as_float(u & 0xffff0000u); }
__device__ inline float sigf(float x){ return 1.0f / (1.0f + __expf(-x)); }

// ---------------- dtype detection ----------------
__global__ void k_detect(const unsigned* __restrict__ xraw,
                         const int* __restrict__ eraw,
                         int* __restrict__ flags)
{
    if (blockIdx.x == 0 && threadIdx.x == 0){
        int bad = 0;
        for (int i = 0; i < 64; ++i){
            unsigned w = xraw[i];
            unsigned h0 = w & 0xffffu, h1 = w >> 16;
            unsigned e0 = (h0 >> 7) & 0xffu, e1 = (h1 >> 7) & 0xffu;
            if (!((h0 & 0x7fffu) == 0 || (e0 >= 97 && e0 <= 157))) ++bad;
            if (!((h1 & 0x7fffu) == 0 || (e1 >= 97 && e1 <= 157))) ++bad;
        }
        flags[0] = (bad > 8) ? 0 : 1;
        int zeroOdd = 0;
        for (int i = 0; i < 64; ++i)
            if (eraw[2 * i + 1] == 0) ++zeroOdd;
        flags[1] = (zeroOdd > 48) ? 1 : 0;
    }
}

__device__ inline int edge_src(const int* ei, int e, int /*ne*/, int i64){
    return i64 ? ei[2 * e] : ei[e];
}
__device__ inline int edge_dst(const int* ei, int e, int ne, int i64){
    return i64 ? ei[2 * (ne + e)] : ei[ne + e];
}

// ---------------- CSR build ----------------
__global__ void k_zero(unsigned* __restrict__ p, int n){
    int i = blockIdx.x * 256 + threadIdx.x;
    if (i < n) p[i] = 0u;
}

__global__ void k_hist(const int* __restrict__ ei, const int* __restrict__ flags,
                       unsigned* __restrict__ cnt, int ne){
    int e = blockIdx.x * 256 + threadIdx.x;
    int i64 = flags[1];
    if (e < ne) atomicAdd(&cnt[edge_dst(ei, e, ne, i64)], 1u);
}

// chunk = 1024 elements per block (256 threads x 4). off[i] = chunk-local exclusive scan.
__global__ __launch_bounds__(256) void k_scan_chunk(
    const unsigned* __restrict__ cnt, unsigned* __restrict__ off,
    unsigned* __restrict__ csums, int n)
{
    __shared__ unsigned wsum[4];
    int base = blockIdx.x * 1024;
    int t = threadIdx.x, lane = t & 63, wv = t >> 6;
    unsigned v[4];
    #pragma unroll
    for (int k = 0; k < 4; ++k){
        int idx = base + t * 4 + k;
        v[k] = (idx < n) ? cnt[idx] : 0u;
    }
    unsigned tsum = v[0] + v[1] + v[2] + v[3];
    unsigned x = tsum;                         // inclusive scan across 64 lanes
    #pragma unroll
    for (int o = 1; o < 64; o <<= 1){
        unsigned y = __shfl_up(x, o, 64);
        if (lane >= o) x += y;
    }
    if (lane == 63) wsum[wv] = x;
    __syncthreads();
    if (t == 0){
        unsigned run = 0;
        #pragma unroll
        for (int w = 0; w < 4; ++w){ unsigned tv = wsum[w]; wsum[w] = run; run += tv; }
        csums[blockIdx.x] = run;               // chunk total
    }
    __syncthreads();
    unsigned exc = x - tsum + wsum[wv];        // exclusive prefix for this thread
    #pragma unroll
    for (int k = 0; k < 4; ++k){
        int idx = base + t * 4 + k;
        if (idx < n) off[idx] = exc;
        exc += v[k];
    }
}

__global__ void k_scan_mid(unsigned* __restrict__ csums, unsigned* __restrict__ cbases, int nch){
    if (threadIdx.x == 0 && blockIdx.x == 0){
        unsigned run = 0;
        for (int c = 0; c < nch; ++c){ unsigned t = csums[c]; cbases[c] = run; run += t; }
    }
}

// finalize: off += chunk base; cur = off (cnt storage reused as cursor); dinv = rsqrt(1+cnt)
__global__ void k_scan_fix(unsigned* __restrict__ off, const unsigned* __restrict__ cbases,
                           unsigned* __restrict__ cntcur, float* __restrict__ dinv,
                           int n, int ne){
    int i = blockIdx.x * 256 + threadIdx.x;
    if (i < n){
        unsigned c = cntcur[i];
        unsigned o = off[i] + cbases[i >> 10];
        off[i] = o;
        cntcur[i] = o;                         // cursor for fill
        dinv[i] = rsqrtf(1.0f + (float)c);     // +1 self loop
    }
    if (i == 0) off[n] = (unsigned)ne;
}

__global__ void k_fill(const int* __restrict__ ei, const int* __restrict__ flags,
                       unsigned* __restrict__ cur, int* __restrict__ csr_src, int ne){
    int e = blockIdx.x * 256 + threadIdx.x;
    int i64 = flags[1];
    if (e < ne){
        int s = edge_src(ei, e, ne, i64);
        int d = edge_dst(ei, e, ne, i64);
        unsigned p = atomicAdd(&cur[d], 1u);
        csr_src[p] = s;
    }
}

// ---------------- linear 1: h1 = x @ W1 ----------------
__global__ __launch_bounds__(256) void k_linear1(
    const unsigned* __restrict__ xraw, const unsigned* __restrict__ w1raw,
    const int* __restrict__ flags, float* __restrict__ h1, int n)
{
    __shared__ float w1s[D_IN * D_HID];     // 32 KB fp32
    __shared__ float xs[16][132];           // pad -> conflict-free broadcast

    const int isBf16 = flags[0];

    if (isBf16){
        const uint4* wv = (const uint4*)w1raw;
        for (int i = threadIdx.x; i < (D_IN * D_HID) / 8; i += 256){
            uint4 u = wv[i];
            float* o = &w1s[i * 8];
            o[0]=bflo(u.x); o[1]=bfhi(u.x); o[2]=bflo(u.y); o[3]=bfhi(u.y);
            o[4]=bflo(u.z); o[5]=bfhi(u.z); o[6]=bflo(u.w); o[7]=bfhi(u.w);
        }
    } else {
        const float4* wv = (const float4*)w1raw;
        for (int i = threadIdx.x; i < (D_IN * D_HID) / 4; i += 256)
            ((float4*)w1s)[i] = wv[i];
    }

    const int ln = threadIdx.x >> 4;
    const int cg = threadIdx.x & 15;

    for (int nb = blockIdx.x * 16; nb < n; nb += gridDim.x * 16){
        {
            int node = nb + ln;
            float4 a, b;
            if (node >= n){
                a = make_float4(0,0,0,0); b = a;
            } else if (isBf16){
                uint4 u = ((const uint4*)xraw)[(size_t)node * (D_IN / 8) + cg];
                a = make_float4(bflo(u.x), bfhi(u.x), bflo(u.y), bfhi(u.y));
                b = make_float4(bflo(u.z), bfhi(u.z), bflo(u.w), bfhi(u.w));
            } else {
                const float4* xr = (const float4*)xraw;
                a = xr[(size_t)node * (D_IN / 4) + cg * 2];
                b = xr[(size_t)node * (D_IN / 4) + cg * 2 + 1];
            }
            float4* o = (float4*)&xs[ln][cg * 8];
            o[0] = a; o[1] = b;
        }
        __syncthreads();

        int node = nb + ln;
        float a0=0.f, a1=0.f, a2=0.f, a3=0.f;
        #pragma unroll 8
        for (int k = 0; k < D_IN; ++k){
            float xv = xs[ln][k];
            const float* wr = &w1s[k * D_HID + cg * 4];
            a0 = fmaf(xv, wr[0], a0);
            a1 = fmaf(xv, wr[1], a1);
            a2 = fmaf(xv, wr[2], a2);
            a3 = fmaf(xv, wr[3], a3);
        }
        if (node < n)
            *(float4*)&h1[(size_t)node * D_HID + cg * 4] = make_float4(a0, a1, a2, a3);
        __syncthreads();
    }
}

// ---------------- aggA: CSR aggregate layer1 + bias + sigmoid -> act ----------------
__global__ __launch_bounds__(256) void k_aggA(
    const unsigned* __restrict__ off, const int* __restrict__ csr_src,
    const float* __restrict__ dinv, const float* __restrict__ h1,
    const unsigned* __restrict__ b1raw, const int* __restrict__ flags,
    float* __restrict__ act, int n)
{
    int lane = threadIdx.x & 63;
    int d = blockIdx.x * 4 + (threadIdx.x >> 6);   // wave per node
    if (d >= n) return;
    float dd = dinv[d];
    float acc = h1[(size_t)d * D_HID + lane] * dd * dd;   // self loop
    int beg = (int)off[d], end = (int)off[d + 1];
    int i = beg;
    for (; i + 4 <= end; i += 4){
        int s0 = csr_src[i], s1 = csr_src[i+1], s2 = csr_src[i+2], s3 = csr_src[i+3];
        float w0 = dinv[s0] * dd, w1 = dinv[s1] * dd, w2 = dinv[s2] * dd, w3 = dinv[s3] * dd;
        float v0 = h1[(size_t)s0 * D_HID + lane];
        float v1 = h1[(size_t)s1 * D_HID + lane];
        float v2 = h1[(size_t)s2 * D_HID + lane];
        float v3 = h1[(size_t)s3 * D_HID + lane];
        acc = fmaf(v0, w0, acc);
        acc = fmaf(v1, w1, acc);
        acc = fmaf(v2, w2, acc);
        acc = fmaf(v3, w3, acc);
    }
    for (; i < end; ++i){
        int s = csr_src[i];
        acc = fmaf(h1[(size_t)s * D_HID + lane], dinv[s] * dd, acc);
    }
    float bv = flags[0] ? __bfloat162float(((const __hip_bfloat16*)b1raw)[lane])
                        : ((const float*)b1raw)[lane];
    act[(size_t)d * D_HID + lane] = sigf(acc + bv);
}

// ---------------- linear 2: h2 = act @ W2 ----------------
__global__ __launch_bounds__(256) void k_linear2(
    const float* __restrict__ act, const unsigned* __restrict__ w2raw,
    const int* __restrict__ flags, float* __restrict__ h2, int n)
{
    __shared__ float w2s[D_HID * D_OUT];    // 4 KB
    __shared__ float as[16][68];

    const int isBf16 = flags[0];

    if (isBf16){
        const uint4* wv = (const uint4*)w2raw;
        for (int i = threadIdx.x; i < (D_HID * D_OUT) / 8; i += 256){
            uint4 u = wv[i];
            float* o = &w2s[i * 8];
            o[0]=bflo(u.x); o[1]=bfhi(u.x); o[2]=bflo(u.y); o[3]=bfhi(u.y);
            o[4]=bflo(u.z); o[5]=bfhi(u.z); o[6]=bflo(u.w); o[7]=bfhi(u.w);
        }
    } else {
        const float4* wv = (const float4*)w2raw;
        for (int i = threadIdx.x; i < (D_HID * D_OUT) / 4; i += 256)
            ((float4*)w2s)[i] = wv[i];
    }

    const int ln  = threadIdx.x >> 4;
    const int col = threadIdx.x & 15;

    for (int nb = blockIdx.x * 16; nb < n; nb += gridDim.x * 16){
        {
            int node = nb + ln;
            float4 v = (node < n) ? *(const float4*)&act[(size_t)node * D_HID + col * 4]
                                  : make_float4(0,0,0,0);
            *(float4*)&as[ln][col * 4] = v;
        }
        __syncthreads();

        int node = nb + ln;
        float acc = 0.f;
        #pragma unroll 8
        for (int k = 0; k < D_HID; ++k)
            acc = fmaf(as[ln][k], w2s[k * D_OUT + col], acc);

        if (node < n) h2[(size_t)node * D_OUT + col] = acc;
        __syncthreads();
    }
}

// ---------------- aggB: CSR aggregate layer2 + bias + log_softmax -> out ----------------
__global__ __launch_bounds__(256) void k_aggB(
    const unsigned* __restrict__ off, const int* __restrict__ csr_src,
    const float* __restrict__ dinv, const float* __restrict__ h2,
    const unsigned* __restrict__ b2raw, const int* __restrict__ flags,
    void* __restrict__ out, int n)
{
    int j = threadIdx.x & 15;
    int d = blockIdx.x * 16 + (threadIdx.x >> 4);  // 16-lane group per node
    int isBf16 = flags[0];
    if (d >= n) return;
    float dd = dinv[d];
    float acc = h2[(size_t)d * D_OUT + j] * dd * dd;  // self loop
    int beg = (int)off[d], end = (int)off[d + 1];
    int i = beg;
    for (; i + 4 <= end; i += 4){
        int s0 = csr_src[i], s1 = csr_src[i+1], s2 = csr_src[i+2], s3 = csr_src[i+3];
        float w0 = dinv[s0] * dd, w1 = dinv[s1] * dd, w2 = dinv[s2] * dd, w3 = dinv[s3] * dd;
        float v0 = h2[(size_t)s0 * D_OUT + j];
        float v1 = h2[(size_t)s1 * D_OUT + j];
        float v2 = h2[(size_t)s2 * D_OUT + j];
        float v3 = h2[(size_t)s3 * D_OUT + j];
        acc = fmaf(v0, w0, acc);
        acc = fmaf(v1, w1, acc);
        acc = fmaf(v2, w2, acc);
        acc = fmaf(v3, w3, acc);
    }
    for (; i < end; ++i){
        int s = csr_src[i];
        acc = fmaf(h2[(size_t)s * D_OUT + j], dinv[s] * dd, acc);
    }
    float bj = isBf16 ? __bfloat162float(((const __hip_bfloat16*)b2raw)[j])
                      : ((const float*)b2raw)[j];
    float v = acc + bj;
    float m = v;
    #pragma unroll
    for (int o = 8; o; o >>= 1) m = fmaxf(m, __shfl_xor(m, o, 16));
    float e = __expf(v - m);
    float s = e;
    #pragma unroll
    for (int o = 8; o; o >>= 1) s += __shfl_xor(s, o, 16);
    float r = v - m - __logf(s);
    if (isBf16) ((__hip_bfloat16*)out)[(size_t)d * D_OUT + j] = __float2bfloat16(r);
    else        ((float*)out)[(size_t)d * D_OUT + j] = r;
}

extern "C" void kernel_launch(void* const* d_in, const int* in_sizes, int n_in,
                              void* d_out, int out_size, void* d_ws, size_t ws_size,
                              hipStream_t stream)
{
    const unsigned* xraw  = (const unsigned*)d_in[0];
    const int*      ei    = (const int*)d_in[1];
    const unsigned* w1raw = (const unsigned*)d_in[2];
    const unsigned* b1raw = (const unsigned*)d_in[3];
    const unsigned* w2raw = (const unsigned*)d_in[4];
    const unsigned* b2raw = (const unsigned*)d_in[5];

    const int n  = in_sizes[0] / D_IN;   // 100000
    const int ne = in_sizes[1] / 2;      // 1600000

    // ws layout (4B words):
    // flags[64] | csums[256] | cbases[256] | dinv[nAl] | cntcur[nAl] | off[nAl+64] | csr[neAl] | bufA[n*64] | bufB[n*64]
    size_t nAl  = ((size_t)n + 255) & ~(size_t)255;
    size_t neAl = ((size_t)ne + 255) & ~(size_t)255;
    int*      flags  = (int*)d_ws;
    unsigned* csums  = (unsigned*)d_ws + 64;
    unsigned* cbases = csums + 256;
    float*    dinv   = (float*)(cbases + 256);
    unsigned* cntcur = (unsigned*)(dinv + nAl);
    unsigned* off    = cntcur + nAl;
    int*      csr    = (int*)(off + nAl + 64);
    float*    bufA   = (float*)(csr + neAl);          // h1, then h2 (h1 dead after aggA)
    float*    bufB   = bufA + (size_t)n * D_HID;      // act
    float*    h2     = bufA;

    const int nch = (n + 1023) / 1024;

    k_detect    <<<1, 64, 0, stream>>>(xraw, ei, flags);
    k_zero      <<<(n + 255) / 256, 256, 0, stream>>>(cntcur, n);
    k_hist      <<<(ne + 255) / 256, 256, 0, stream>>>(ei, flags, cntcur, ne);
    k_scan_chunk<<<nch, 256, 0, stream>>>(cntcur, off, csums, n);
    k_scan_mid  <<<1, 64, 0, stream>>>(csums, cbases, nch);
    k_scan_fix  <<<(n + 255) / 256, 256, 0, stream>>>(off, cbases, cntcur, dinv, n, ne);
    k_fill      <<<(ne + 255) / 256, 256, 0, stream>>>(ei, flags, cntcur, csr, ne);

    k_linear1   <<<768, 256, 0, stream>>>(xraw, w1raw, flags, bufA, n);
    k_aggA      <<<(n + 3) / 4, 256, 0, stream>>>(off, csr, dinv, bufA, b1raw, flags, bufB, n);
    k_linear2   <<<768, 256, 0, stream>>>(bufB, w2raw, flags, h2, n);
    k_aggB      <<<(n + 15) / 16, 256, 0, stream>>>(off, csr, dinv, h2, b2raw, flags, d_out, n);
}

// Round 5
// 324.588 us; speedup vs baseline: 2.1180x; 1.3986x over previous
//
#include <hip/hip_runtime.h>
#include <hip/hip_bf16.h>

// GCN 2-layer, CSR aggregation with bucketized CSR build (no device-scope
// atomic scatter in the hot path; all histogram/cursor atomics in LDS).
// flags[0]=1 if floats bf16 else fp32; flags[1]=1 if edge_index int64 else int32.

constexpr int D_IN  = 128;
constexpr int D_HID = 64;
constexpr int D_OUT = 16;

constexpr int WSHIFT  = 10;      // bucket = dst >> 10 (1024 nodes/bucket)
constexpr int MAXB    = 128;     // max buckets supported (n <= 131072)
constexpr int BCAP    = 24576;   // bucket capacity (mean 16384, +64 sigma)
constexpr int BIN_CAP = 48;      // LDS bin cap per bucket per 2048-edge chunk
constexpr int CHUNK   = 2048;

__device__ inline float bflo(unsigned u){ return __uint_as_float(u << 16); }
__device__ inline float bfhi(unsigned u){ return __uint_as_float(u & 0xffff0000u); }
__device__ inline float sigf(float x){ return 1.0f / (1.0f + __expf(-x)); }

// ---------------- dtype detection ----------------
__global__ void k_detect(const unsigned* __restrict__ xraw,
                         const int* __restrict__ eraw,
                         int* __restrict__ flags)
{
    if (blockIdx.x == 0 && threadIdx.x == 0){
        int bad = 0;
        for (int i = 0; i < 64; ++i){
            unsigned w = xraw[i];
            unsigned h0 = w & 0xffffu, h1 = w >> 16;
            unsigned e0 = (h0 >> 7) & 0xffu, e1 = (h1 >> 7) & 0xffu;
            if (!((h0 & 0x7fffu) == 0 || (e0 >= 97 && e0 <= 157))) ++bad;
            if (!((h1 & 0x7fffu) == 0 || (e1 >= 97 && e1 <= 157))) ++bad;
        }
        flags[0] = (bad > 8) ? 0 : 1;
        int zeroOdd = 0;
        for (int i = 0; i < 64; ++i)
            if (eraw[2 * i + 1] == 0) ++zeroOdd;
        flags[1] = (zeroOdd > 48) ? 1 : 0;
    }
}

__global__ void k_zero128(unsigned* __restrict__ p){
    p[threadIdx.x] = 0u;
}

// ---------------- phase 1: bucketize edges by dst>>10 ----------------
// Each block: one 2048-edge chunk. LDS bins -> contiguous run flush to gbuf.
__global__ __launch_bounds__(256) void k_bucketize(
    const int* __restrict__ ei, const int* __restrict__ flags,
    unsigned* __restrict__ gcur, uint2* __restrict__ gbuf, int ne, int B)
{
    __shared__ unsigned bcnt[MAXB];
    __shared__ unsigned bbase[MAXB];
    __shared__ uint2 bins[MAXB * BIN_CAP];   // 48 KB

    const int t = threadIdx.x, lane = t & 63, wv = t >> 6;
    const int i64 = flags[1];
    const int e0 = blockIdx.x * CHUNK;

    if (t < MAXB) bcnt[t] = 0u;
    __syncthreads();

    #pragma unroll
    for (int k = 0; k < CHUNK / 256; ++k){
        int e = e0 + k * 256 + t;
        if (e < ne){
            int s, d;
            if (i64){ s = ei[2 * e]; d = ei[2 * (ne + e)]; }
            else    { s = ei[e];     d = ei[ne + e]; }
            int b = d >> WSHIFT;
            unsigned p = atomicAdd(&bcnt[b], 1u);
            if (p < (unsigned)BIN_CAP){
                bins[b * BIN_CAP + p] = make_uint2((unsigned)s, (unsigned)d);
            } else {                                   // rare overflow: direct
                unsigned g = atomicAdd(&gcur[b], 1u);
                gbuf[(size_t)b * BCAP + g] = make_uint2((unsigned)s, (unsigned)d);
            }
        }
    }
    __syncthreads();

    if (t < B){
        unsigned c = min(bcnt[t], (unsigned)BIN_CAP);
        bbase[t] = atomicAdd(&gcur[t], c);             // reserve contiguous run
    }
    __syncthreads();

    for (int b = wv; b < B; b += 4){
        unsigned c = min(bcnt[b], (unsigned)BIN_CAP);
        if ((unsigned)lane < c)
            gbuf[(size_t)b * BCAP + bbase[b] + lane] = bins[b * BIN_CAP + lane];
    }
}

// ---------------- phase 2: per-bucket hist + scan + csr fill (LDS atomics only) ----------------
__global__ __launch_bounds__(256) void k_build(
    const uint2* __restrict__ gbuf, const unsigned* __restrict__ gcnt,
    unsigned* __restrict__ off, float* __restrict__ dinv, int* __restrict__ csr,
    int n, int B)
{
    __shared__ unsigned hist[1024];
    __shared__ unsigned offl[1024];
    __shared__ unsigned wsums[4];
    __shared__ unsigned gsc[MAXB];
    __shared__ unsigned bb_s;

    const int t = threadIdx.x, lane = t & 63, wv = t >> 6;
    const int b = blockIdx.x;
    const int base = b << WSHIFT;
    const int nodes = min(1024, n - base);

    if (t < B) gsc[t] = gcnt[t];
    for (int i = t; i < 1024; i += 256) hist[i] = 0u;
    __syncthreads();
    if (t == 0){
        unsigned s = 0;
        for (int i = 0; i < b; ++i) s += gsc[i];
        bb_s = s;
    }
    const unsigned cnt = gsc[b];
    const uint2* mybuf = gbuf + (size_t)b * BCAP;

    // histogram (LDS atomics)
    for (unsigned i = t; i < cnt; i += 256)
        atomicAdd(&hist[mybuf[i].y - base], 1u);
    __syncthreads();

    // exclusive scan of 1024 counters (thread: 4 contiguous)
    unsigned v[4];
    #pragma unroll
    for (int k = 0; k < 4; ++k) v[k] = hist[t * 4 + k];
    unsigned ts = v[0] + v[1] + v[2] + v[3];
    unsigned x = ts;
    #pragma unroll
    for (int o = 1; o < 64; o <<= 1){
        unsigned y = __shfl_up(x, o, 64);
        if (lane >= o) x += y;
    }
    if (lane == 63) wsums[wv] = x;
    __syncthreads();
    if (t == 0){
        unsigned run = 0;
        #pragma unroll
        for (int w = 0; w < 4; ++w){ unsigned tv = wsums[w]; wsums[w] = run; run += tv; }
    }
    __syncthreads();
    unsigned exc = x - ts + wsums[wv];
    #pragma unroll
    for (int k = 0; k < 4; ++k){ offl[t * 4 + k] = exc; exc += v[k]; }
    __syncthreads();

    const unsigned bb = bb_s;
    // write off / dinv
    for (int i = t; i < nodes; i += 256){
        off[base + i] = bb + offl[i];
        dinv[base + i] = rsqrtf(1.0f + (float)hist[i]);
    }
    if (b == B - 1 && t == 0) off[n] = bb + cnt;
    __syncthreads();

    // cursors <- local offsets
    for (int i = t; i < 1024; i += 256) hist[i] = offl[i];
    __syncthreads();

    // fill csr slice (writes confined to this block's contiguous region)
    for (unsigned i = t; i < cnt; i += 256){
        uint2 e = mybuf[i];
        unsigned p = atomicAdd(&hist[e.y - base], 1u);
        csr[bb + p] = (int)e.x;
    }
}

// ---------------- linear 1: h1 = x @ W1 ----------------
__global__ __launch_bounds__(256) void k_linear1(
    const unsigned* __restrict__ xraw, const unsigned* __restrict__ w1raw,
    const int* __restrict__ flags, float* __restrict__ h1, int n)
{
    __shared__ float w1s[D_IN * D_HID];
    __shared__ float xs[16][132];

    const int isBf16 = flags[0];

    if (isBf16){
        const uint4* wv = (const uint4*)w1raw;
        for (int i = threadIdx.x; i < (D_IN * D_HID) / 8; i += 256){
            uint4 u = wv[i];
            float* o = &w1s[i * 8];
            o[0]=bflo(u.x); o[1]=bfhi(u.x); o[2]=bflo(u.y); o[3]=bfhi(u.y);
            o[4]=bflo(u.z); o[5]=bfhi(u.z); o[6]=bflo(u.w); o[7]=bfhi(u.w);
        }
    } else {
        const float4* wv = (const float4*)w1raw;
        for (int i = threadIdx.x; i < (D_IN * D_HID) / 4; i += 256)
            ((float4*)w1s)[i] = wv[i];
    }

    const int ln = threadIdx.x >> 4;
    const int cg = threadIdx.x & 15;

    for (int nb = blockIdx.x * 16; nb < n; nb += gridDim.x * 16){
        {
            int node = nb + ln;
            float4 a, b;
            if (node >= n){
                a = make_float4(0,0,0,0); b = a;
            } else if (isBf16){
                uint4 u = ((const uint4*)xraw)[(size_t)node * (D_IN / 8) + cg];
                a = make_float4(bflo(u.x), bfhi(u.x), bflo(u.y), bfhi(u.y));
                b = make_float4(bflo(u.z), bfhi(u.z), bflo(u.w), bfhi(u.w));
            } else {
                const float4* xr = (const float4*)xraw;
                a = xr[(size_t)node * (D_IN / 4) + cg * 2];
                b = xr[(size_t)node * (D_IN / 4) + cg * 2 + 1];
            }
            float4* o = (float4*)&xs[ln][cg * 8];
            o[0] = a; o[1] = b;
        }
        __syncthreads();

        int node = nb + ln;
        float a0=0.f, a1=0.f, a2=0.f, a3=0.f;
        #pragma unroll 8
        for (int k = 0; k < D_IN; ++k){
            float xv = xs[ln][k];
            const float* wr = &w1s[k * D_HID + cg * 4];
            a0 = fmaf(xv, wr[0], a0);
            a1 = fmaf(xv, wr[1], a1);
            a2 = fmaf(xv, wr[2], a2);
            a3 = fmaf(xv, wr[3], a3);
        }
        if (node < n)
            *(float4*)&h1[(size_t)node * D_HID + cg * 4] = make_float4(a0, a1, a2, a3);
        __syncthreads();
    }
}

// ---------------- aggA: CSR aggregate + bias + sigmoid -> act ----------------
__global__ __launch_bounds__(256) void k_aggA(
    const unsigned* __restrict__ off, const int* __restrict__ csr_src,
    const float* __restrict__ dinv, const float* __restrict__ h1,
    const unsigned* __restrict__ b1raw, const int* __restrict__ flags,
    float* __restrict__ act, int n)
{
    int lane = threadIdx.x & 63;
    int d = blockIdx.x * 4 + (threadIdx.x >> 6);
    if (d >= n) return;
    float dd = dinv[d];
    float acc = h1[(size_t)d * D_HID + lane] * dd * dd;
    int beg = (int)off[d], end = (int)off[d + 1];
    int i = beg;
    for (; i + 4 <= end; i += 4){
        int s0 = csr_src[i], s1 = csr_src[i+1], s2 = csr_src[i+2], s3 = csr_src[i+3];
        float w0 = dinv[s0] * dd, w1 = dinv[s1] * dd, w2 = dinv[s2] * dd, w3 = dinv[s3] * dd;
        float v0 = h1[(size_t)s0 * D_HID + lane];
        float v1 = h1[(size_t)s1 * D_HID + lane];
        float v2 = h1[(size_t)s2 * D_HID + lane];
        float v3 = h1[(size_t)s3 * D_HID + lane];
        acc = fmaf(v0, w0, acc);
        acc = fmaf(v1, w1, acc);
        acc = fmaf(v2, w2, acc);
        acc = fmaf(v3, w3, acc);
    }
    for (; i < end; ++i){
        int s = csr_src[i];
        acc = fmaf(h1[(size_t)s * D_HID + lane], dinv[s] * dd, acc);
    }
    float bv = flags[0] ? __bfloat162float(((const __hip_bfloat16*)b1raw)[lane])
                        : ((const float*)b1raw)[lane];
    act[(size_t)d * D_HID + lane] = sigf(acc + bv);
}

// ---------------- linear 2: h2 = act @ W2 ----------------
__global__ __launch_bounds__(256) void k_linear2(
    const float* __restrict__ act, const unsigned* __restrict__ w2raw,
    const int* __restrict__ flags, float* __restrict__ h2, int n)
{
    __shared__ float w2s[D_HID * D_OUT];
    __shared__ float as[16][68];

    const int isBf16 = flags[0];

    if (isBf16){
        const uint4* wv = (const uint4*)w2raw;
        for (int i = threadIdx.x; i < (D_HID * D_OUT) / 8; i += 256){
            uint4 u = wv[i];
            float* o = &w2s[i * 8];
            o[0]=bflo(u.x); o[1]=bfhi(u.x); o[2]=bflo(u.y); o[3]=bfhi(u.y);
            o[4]=bflo(u.z); o[5]=bfhi(u.z); o[6]=bflo(u.w); o[7]=bfhi(u.w);
        }
    } else {
        const float4* wv = (const float4*)w2raw;
        for (int i = threadIdx.x; i < (D_HID * D_OUT) / 4; i += 256)
            ((float4*)w2s)[i] = wv[i];
    }

    const int ln  = threadIdx.x >> 4;
    const int col = threadIdx.x & 15;

    for (int nb = blockIdx.x * 16; nb < n; nb += gridDim.x * 16){
        {
            int node = nb + ln;
            float4 v = (node < n) ? *(const float4*)&act[(size_t)node * D_HID + col * 4]
                                  : make_float4(0,0,0,0);
            *(float4*)&as[ln][col * 4] = v;
        }
        __syncthreads();

        int node = nb + ln;
        float acc = 0.f;
        #pragma unroll 8
        for (int k = 0; k < D_HID; ++k)
            acc = fmaf(as[ln][k], w2s[k * D_OUT + col], acc);

        if (node < n) h2[(size_t)node * D_OUT + col] = acc;
        __syncthreads();
    }
}

// ---------------- aggB: CSR aggregate + bias + log_softmax -> out ----------------
__global__ __launch_bounds__(256) void k_aggB(
    const unsigned* __restrict__ off, const int* __restrict__ csr_src,
    const float* __restrict__ dinv, const float* __restrict__ h2,
    const unsigned* __restrict__ b2raw, const int* __restrict__ flags,
    void* __restrict__ out, int n)
{
    int j = threadIdx.x & 15;
    int d = blockIdx.x * 16 + (threadIdx.x >> 4);
    int isBf16 = flags[0];
    if (d >= n) return;
    float dd = dinv[d];
    float acc = h2[(size_t)d * D_OUT + j] * dd * dd;
    int beg = (int)off[d], end = (int)off[d + 1];
    int i = beg;
    for (; i + 4 <= end; i += 4){
        int s0 = csr_src[i], s1 = csr_src[i+1], s2 = csr_src[i+2], s3 = csr_src[i+3];
        float w0 = dinv[s0] * dd, w1 = dinv[s1] * dd, w2 = dinv[s2] * dd, w3 = dinv[s3] * dd;
        float v0 = h2[(size_t)s0 * D_OUT + j];
        float v1 = h2[(size_t)s1 * D_OUT + j];
        float v2 = h2[(size_t)s2 * D_OUT + j];
        float v3 = h2[(size_t)s3 * D_OUT + j];
        acc = fmaf(v0, w0, acc);
        acc = fmaf(v1, w1, acc);
        acc = fmaf(v2, w2, acc);
        acc = fmaf(v3, w3, acc);
    }
    for (; i < end; ++i){
        int s = csr_src[i];
        acc = fmaf(h2[(size_t)s * D_OUT + j], dinv[s] * dd, acc);
    }
    float bj = isBf16 ? __bfloat162float(((const __hip_bfloat16*)b2raw)[j])
                      : ((const float*)b2raw)[j];
    float v = acc + bj;
    float m = v;
    #pragma unroll
    for (int o = 8; o; o >>= 1) m = fmaxf(m, __shfl_xor(m, o, 16));
    float e = __expf(v - m);
    float s = e;
    #pragma unroll
    for (int o = 8; o; o >>= 1) s += __shfl_xor(s, o, 16);
    float r = v - m - __logf(s);
    if (isBf16) ((__hip_bfloat16*)out)[(size_t)d * D_OUT + j] = __float2bfloat16(r);
    else        ((float*)out)[(size_t)d * D_OUT + j] = r;
}

extern "C" void kernel_launch(void* const* d_in, const int* in_sizes, int n_in,
                              void* d_out, int out_size, void* d_ws, size_t ws_size,
                              hipStream_t stream)
{
    const unsigned* xraw  = (const unsigned*)d_in[0];
    const int*      ei    = (const int*)d_in[1];
    const unsigned* w1raw = (const unsigned*)d_in[2];
    const unsigned* b1raw = (const unsigned*)d_in[3];
    const unsigned* w2raw = (const unsigned*)d_in[4];
    const unsigned* b2raw = (const unsigned*)d_in[5];

    const int n  = in_sizes[0] / D_IN;   // 100000
    const int ne = in_sizes[1] / 2;      // 1600000
    const int B  = (n + 1023) >> WSHIFT; // 98 buckets

    // ws layout (4B words):
    // flags[64] | gcur[128] | dinv[nAl] | off[nAl+64] | csr[neAl] | bufA[n*64] | bufB[n*64]
    // gbuf (uint2, B*BCAP) aliases bufA (dead until k_linear1).
    size_t nAl  = ((size_t)n + 255) & ~(size_t)255;
    size_t neAl = ((size_t)ne + 255) & ~(size_t)255;
    int*      flags = (int*)d_ws;
    unsigned* gcur  = (unsigned*)d_ws + 64;
    float*    dinv  = (float*)(gcur + 128);
    unsigned* off   = (unsigned*)(dinv + nAl);
    int*      csr   = (int*)(off + nAl + 64);
    float*    bufA  = (float*)(csr + neAl);
    float*    bufB  = bufA + (size_t)n * D_HID;
    uint2*    gbuf  = (uint2*)bufA;
    float*    h2    = bufA;

    const int nchunk = (ne + CHUNK - 1) / CHUNK;

    k_detect    <<<1, 64, 0, stream>>>(xraw, ei, flags);
    k_zero128   <<<1, 128, 0, stream>>>(gcur);
    k_bucketize <<<nchunk, 256, 0, stream>>>(ei, flags, gcur, gbuf, ne, B);
    k_build     <<<B, 256, 0, stream>>>(gbuf, gcur, off, dinv, csr, n, B);

    k_linear1   <<<768, 256, 0, stream>>>(xraw, w1raw, flags, bufA, n);
    k_aggA      <<<(n + 3) / 4, 256, 0, stream>>>(off, csr, dinv, bufA, b1raw, flags, bufB, n);
    k_linear2   <<<768, 256, 0, stream>>>(bufB, w2raw, flags, h2, n);
    k_aggB      <<<(n + 15) / 16, 256, 0, stream>>>(off, csr, dinv, h2, b2raw, flags, d_out, n);
}

// Round 6
// 309.513 us; speedup vs baseline: 2.2211x; 1.0487x over previous
//
#include <hip/hip_runtime.h>
#include <hip/hip_bf16.h>

// GCN 2-layer, CSR aggregation, bf16 intermediates (fp32 accumulation).
// flags[0]=1 if floats bf16 else fp32; flags[1]=1 if edge_index int64 else int32.
// Bucketized CSR build: packed (src<<10 | dst_local) records, LDS-only histogram atomics.

constexpr int D_IN  = 128;
constexpr int D_HID = 64;
constexpr int D_OUT = 16;

constexpr int WSHIFT  = 10;      // bucket = dst >> 10 (1024 nodes/bucket)
constexpr int MAXB    = 128;     // max buckets (n <= 131072; src fits 17 bits + 10 local)
constexpr int BCAP    = 24576;   // bucket capacity (mean 16384 at E/N=16)
constexpr int BIN_CAP = 48;      // LDS bin cap per bucket per chunk
constexpr int CHUNK   = 2048;

__device__ inline float bflo(unsigned u){ return __uint_as_float(u << 16); }
__device__ inline float bfhi(unsigned u){ return __uint_as_float(u & 0xffff0000u); }
__device__ inline float bfu (unsigned short u){ return __uint_as_float(((unsigned)u) << 16); }
__device__ inline unsigned short f2bu(float f){
    __hip_bfloat16 h = __float2bfloat16(f);
    return *reinterpret_cast<unsigned short*>(&h);
}
__device__ inline float sigf(float x){ return 1.0f / (1.0f + __expf(-x)); }

// ---------------- dtype detection + gcur zero ----------------
__global__ void k_detect(const unsigned* __restrict__ xraw,
                         const int* __restrict__ eraw,
                         int* __restrict__ flags, unsigned* __restrict__ gcur)
{
    int t = threadIdx.x;
    if (t < 128) gcur[t] = 0u;
    if (t == 0){
        int bad = 0;
        for (int i = 0; i < 64; ++i){
            unsigned w = xraw[i];
            unsigned h0 = w & 0xffffu, h1 = w >> 16;
            unsigned e0 = (h0 >> 7) & 0xffu, e1 = (h1 >> 7) & 0xffu;
            if (!((h0 & 0x7fffu) == 0 || (e0 >= 97 && e0 <= 157))) ++bad;
            if (!((h1 & 0x7fffu) == 0 || (e1 >= 97 && e1 <= 157))) ++bad;
        }
        flags[0] = (bad > 8) ? 0 : 1;
        int zeroOdd = 0;
        for (int i = 0; i < 64; ++i)
            if (eraw[2 * i + 1] == 0) ++zeroOdd;
        flags[1] = (zeroOdd > 48) ? 1 : 0;
    }
}

// ---------------- phase 1: bucketize edges by dst>>10, packed 4B records ----------------
__global__ __launch_bounds__(256) void k_bucketize(
    const int* __restrict__ ei, const int* __restrict__ flags,
    unsigned* __restrict__ gcur, unsigned* __restrict__ gbuf, int ne, int B)
{
    __shared__ unsigned bcnt[MAXB];
    __shared__ unsigned bbase[MAXB];
    __shared__ unsigned bins[MAXB * BIN_CAP];   // 24.6 KB

    const int t = threadIdx.x, lane = t & 63, wv = t >> 6;
    const int i64 = flags[1];
    const int e0 = blockIdx.x * CHUNK;

    if (t < MAXB) bcnt[t] = 0u;
    __syncthreads();

    #pragma unroll
    for (int k = 0; k < CHUNK / 256; ++k){
        int e = e0 + k * 256 + t;
        if (e < ne){
            int s, d;
            if (i64){ s = ei[2 * e]; d = ei[2 * (ne + e)]; }
            else    { s = ei[e];     d = ei[ne + e]; }
            int b = d >> WSHIFT;
            unsigned v = ((unsigned)s << WSHIFT) | ((unsigned)d & ((1u << WSHIFT) - 1));
            unsigned p = atomicAdd(&bcnt[b], 1u);
            if (p < (unsigned)BIN_CAP){
                bins[b * BIN_CAP + p] = v;
            } else {                                   // rare overflow: direct
                unsigned g = atomicAdd(&gcur[b], 1u);
                gbuf[(size_t)b * BCAP + g] = v;
            }
        }
    }
    __syncthreads();

    if (t < B){
        unsigned c = min(bcnt[t], (unsigned)BIN_CAP);
        bbase[t] = atomicAdd(&gcur[t], c);             // reserve contiguous run
    }
    __syncthreads();

    for (int b = wv; b < B; b += 4){
        unsigned c = min(bcnt[b], (unsigned)BIN_CAP);
        if ((unsigned)lane < c)
            gbuf[(size_t)b * BCAP + bbase[b] + lane] = bins[b * BIN_CAP + lane];
    }
}

// ---------------- phase 2: per-bucket hist + scan + csr fill (LDS atomics only) ----------------
__global__ __launch_bounds__(256) void k_build(
    const unsigned* __restrict__ gbuf, const unsigned* __restrict__ gcnt,
    unsigned* __restrict__ off, float* __restrict__ dinv, int* __restrict__ csr,
    int n, int B)
{
    __shared__ unsigned hist[1024];
    __shared__ unsigned offl[1024];
    __shared__ unsigned wsums[4];
    __shared__ unsigned gsc[MAXB];
    __shared__ unsigned bb_s;

    const int t = threadIdx.x, lane = t & 63, wv = t >> 6;
    const int b = blockIdx.x;
    const int base = b << WSHIFT;
    const int nodes = min(1024, n - base);

    if (t < B) gsc[t] = gcnt[t];
    for (int i = t; i < 1024; i += 256) hist[i] = 0u;
    __syncthreads();
    if (t == 0){
        unsigned s = 0;
        for (int i = 0; i < b; ++i) s += gsc[i];
        bb_s = s;
    }
    const unsigned cnt = gsc[b];
    const unsigned* mybuf = gbuf + (size_t)b * BCAP;

    for (unsigned i = t; i < cnt; i += 256)
        atomicAdd(&hist[mybuf[i] & ((1u << WSHIFT) - 1)], 1u);
    __syncthreads();

    unsigned v[4];
    #pragma unroll
    for (int k = 0; k < 4; ++k) v[k] = hist[t * 4 + k];
    unsigned ts = v[0] + v[1] + v[2] + v[3];
    unsigned x = ts;
    #pragma unroll
    for (int o = 1; o < 64; o <<= 1){
        unsigned y = __shfl_up(x, o, 64);
        if (lane >= o) x += y;
    }
    if (lane == 63) wsums[wv] = x;
    __syncthreads();
    if (t == 0){
        unsigned run = 0;
        #pragma unroll
        for (int w = 0; w < 4; ++w){ unsigned tv = wsums[w]; wsums[w] = run; run += tv; }
    }
    __syncthreads();
    unsigned exc = x - ts + wsums[wv];
    #pragma unroll
    for (int k = 0; k < 4; ++k){ offl[t * 4 + k] = exc; exc += v[k]; }
    __syncthreads();

    const unsigned bb = bb_s;
    for (int i = t; i < nodes; i += 256){
        off[base + i] = bb + offl[i];
        dinv[base + i] = rsqrtf(1.0f + (float)hist[i]);
    }
    if (b == B - 1 && t == 0) off[n] = bb + cnt;
    __syncthreads();

    for (int i = t; i < 1024; i += 256) hist[i] = offl[i];
    __syncthreads();

    for (unsigned i = t; i < cnt; i += 256){
        unsigned rec = mybuf[i];
        unsigned p = atomicAdd(&hist[rec & ((1u << WSHIFT) - 1)], 1u);
        csr[bb + p] = (int)(rec >> WSHIFT);
    }
}

// ---------------- linear 1: h1(bf16) = x @ W1 ----------------
__global__ __launch_bounds__(256) void k_linear1(
    const unsigned* __restrict__ xraw, const unsigned* __restrict__ w1raw,
    const int* __restrict__ flags, unsigned short* __restrict__ h1b, int n)
{
    __shared__ float w1s[D_IN * D_HID];
    __shared__ float xs[16][132];

    const int isBf16 = flags[0];

    if (isBf16){
        const uint4* wv = (const uint4*)w1raw;
        for (int i = threadIdx.x; i < (D_IN * D_HID) / 8; i += 256){
            uint4 u = wv[i];
            float* o = &w1s[i * 8];
            o[0]=bflo(u.x); o[1]=bfhi(u.x); o[2]=bflo(u.y); o[3]=bfhi(u.y);
            o[4]=bflo(u.z); o[5]=bfhi(u.z); o[6]=bflo(u.w); o[7]=bfhi(u.w);
        }
    } else {
        const float4* wv = (const float4*)w1raw;
        for (int i = threadIdx.x; i < (D_IN * D_HID) / 4; i += 256)
            ((float4*)w1s)[i] = wv[i];
    }

    const int ln = threadIdx.x >> 4;
    const int cg = threadIdx.x & 15;

    for (int nb = blockIdx.x * 16; nb < n; nb += gridDim.x * 16){
        {
            int node = nb + ln;
            float4 a, b;
            if (node >= n){
                a = make_float4(0,0,0,0); b = a;
            } else if (isBf16){
                uint4 u = ((const uint4*)xraw)[(size_t)node * (D_IN / 8) + cg];
                a = make_float4(bflo(u.x), bfhi(u.x), bflo(u.y), bfhi(u.y));
                b = make_float4(bflo(u.z), bfhi(u.z), bflo(u.w), bfhi(u.w));
            } else {
                const float4* xr = (const float4*)xraw;
                a = xr[(size_t)node * (D_IN / 4) + cg * 2];
                b = xr[(size_t)node * (D_IN / 4) + cg * 2 + 1];
            }
            float4* o = (float4*)&xs[ln][cg * 8];
            o[0] = a; o[1] = b;
        }
        __syncthreads();

        int node = nb + ln;
        float a0=0.f, a1=0.f, a2=0.f, a3=0.f;
        #pragma unroll 8
        for (int k = 0; k < D_IN; ++k){
            float xv = xs[ln][k];
            const float* wr = &w1s[k * D_HID + cg * 4];
            a0 = fmaf(xv, wr[0], a0);
            a1 = fmaf(xv, wr[1], a1);
            a2 = fmaf(xv, wr[2], a2);
            a3 = fmaf(xv, wr[3], a3);
        }
        if (node < n){
            uint2 pk;
            pk.x = (unsigned)f2bu(a0) | ((unsigned)f2bu(a1) << 16);
            pk.y = (unsigned)f2bu(a2) | ((unsigned)f2bu(a3) << 16);
            *(uint2*)&h1b[(size_t)node * D_HID + cg * 4] = pk;
        }
        __syncthreads();
    }
}

// ---------------- aggA: CSR aggregate (bf16 gather) + bias + sigmoid -> act(bf16) ----------------
__global__ __launch_bounds__(256) void k_aggA(
    const unsigned* __restrict__ off, const int* __restrict__ csr_src,
    const float* __restrict__ dinv, const unsigned short* __restrict__ h1b,
    const unsigned* __restrict__ b1raw, const int* __restrict__ flags,
    unsigned short* __restrict__ actb, int n)
{
    int lane = threadIdx.x & 63;
    int d = blockIdx.x * 4 + (threadIdx.x >> 6);
    if (d >= n) return;
    float dd = dinv[d];
    float acc = bfu(h1b[(size_t)d * D_HID + lane]) * dd * dd;
    int beg = (int)off[d], end = (int)off[d + 1];
    int i = beg;
    for (; i + 4 <= end; i += 4){
        int s0 = csr_src[i], s1 = csr_src[i+1], s2 = csr_src[i+2], s3 = csr_src[i+3];
        float w0 = dinv[s0] * dd, w1 = dinv[s1] * dd, w2 = dinv[s2] * dd, w3 = dinv[s3] * dd;
        float v0 = bfu(h1b[(size_t)s0 * D_HID + lane]);
        float v1 = bfu(h1b[(size_t)s1 * D_HID + lane]);
        float v2 = bfu(h1b[(size_t)s2 * D_HID + lane]);
        float v3 = bfu(h1b[(size_t)s3 * D_HID + lane]);
        acc = fmaf(v0, w0, acc);
        acc = fmaf(v1, w1, acc);
        acc = fmaf(v2, w2, acc);
        acc = fmaf(v3, w3, acc);
    }
    for (; i < end; ++i){
        int s = csr_src[i];
        acc = fmaf(bfu(h1b[(size_t)s * D_HID + lane]), dinv[s] * dd, acc);
    }
    float bv = flags[0] ? __bfloat162float(((const __hip_bfloat16*)b1raw)[lane])
                        : ((const float*)b1raw)[lane];
    actb[(size_t)d * D_HID + lane] = f2bu(sigf(acc + bv));
}

// ---------------- linear 2: h2(bf16) = act(bf16) @ W2 ----------------
__global__ __launch_bounds__(256) void k_linear2(
    const unsigned short* __restrict__ actb, const unsigned* __restrict__ w2raw,
    const int* __restrict__ flags, unsigned short* __restrict__ h2b, int n)
{
    __shared__ float w2s[D_HID * D_OUT];
    __shared__ float as[16][68];

    const int isBf16 = flags[0];

    if (isBf16){
        const uint4* wv = (const uint4*)w2raw;
        for (int i = threadIdx.x; i < (D_HID * D_OUT) / 8; i += 256){
            uint4 u = wv[i];
            float* o = &w2s[i * 8];
            o[0]=bflo(u.x); o[1]=bfhi(u.x); o[2]=bflo(u.y); o[3]=bfhi(u.y);
            o[4]=bflo(u.z); o[5]=bfhi(u.z); o[6]=bflo(u.w); o[7]=bfhi(u.w);
        }
    } else {
        const float4* wv = (const float4*)w2raw;
        for (int i = threadIdx.x; i < (D_HID * D_OUT) / 4; i += 256)
            ((float4*)w2s)[i] = wv[i];
    }

    const int ln  = threadIdx.x >> 4;
    const int col = threadIdx.x & 15;

    for (int nb = blockIdx.x * 16; nb < n; nb += gridDim.x * 16){
        {
            int node = nb + ln;
            uint2 u = make_uint2(0u, 0u);
            if (node < n)
                u = *(const uint2*)&actb[(size_t)node * D_HID + col * 4];
            float* o = &as[ln][col * 4];
            o[0] = bflo(u.x); o[1] = bfhi(u.x);
            o[2] = bflo(u.y); o[3] = bfhi(u.y);
        }
        __syncthreads();

        int node = nb + ln;
        float acc = 0.f;
        #pragma unroll 8
        for (int k = 0; k < D_HID; ++k)
            acc = fmaf(as[ln][k], w2s[k * D_OUT + col], acc);

        if (node < n) h2b[(size_t)node * D_OUT + col] = f2bu(acc);
        __syncthreads();
    }
}

// ---------------- aggB: CSR aggregate (bf16 gather) + bias + log_softmax -> out ----------------
__global__ __launch_bounds__(256) void k_aggB(
    const unsigned* __restrict__ off, const int* __restrict__ csr_src,
    const float* __restrict__ dinv, const unsigned short* __restrict__ h2b,
    const unsigned* __restrict__ b2raw, const int* __restrict__ flags,
    void* __restrict__ out, int n)
{
    int j = threadIdx.x & 15;
    int d = blockIdx.x * 16 + (threadIdx.x >> 4);
    int isBf16 = flags[0];
    if (d >= n) return;
    float dd = dinv[d];
    float acc = bfu(h2b[(size_t)d * D_OUT + j]) * dd * dd;
    int beg = (int)off[d], end = (int)off[d + 1];
    int i = beg;
    for (; i + 4 <= end; i += 4){
        int s0 = csr_src[i], s1 = csr_src[i+1], s2 = csr_src[i+2], s3 = csr_src[i+3];
        float w0 = dinv[s0] * dd, w1 = dinv[s1] * dd, w2 = dinv[s2] * dd, w3 = dinv[s3] * dd;
        float v0 = bfu(h2b[(size_t)s0 * D_OUT + j]);
        float v1 = bfu(h2b[(size_t)s1 * D_OUT + j]);
        float v2 = bfu(h2b[(size_t)s2 * D_OUT + j]);
        float v3 = bfu(h2b[(size_t)s3 * D_OUT + j]);
        acc = fmaf(v0, w0, acc);
        acc = fmaf(v1, w1, acc);
        acc = fmaf(v2, w2, acc);
        acc = fmaf(v3, w3, acc);
    }
    for (; i < end; ++i){
        int s = csr_src[i];
        acc = fmaf(bfu(h2b[(size_t)s * D_OUT + j]), dinv[s] * dd, acc);
    }
    float bj = isBf16 ? __bfloat162float(((const __hip_bfloat16*)b2raw)[j])
                      : ((const float*)b2raw)[j];
    float v = acc + bj;
    float m = v;
    #pragma unroll
    for (int o = 8; o; o >>= 1) m = fmaxf(m, __shfl_xor(m, o, 16));
    float e = __expf(v - m);
    float s = e;
    #pragma unroll
    for (int o = 8; o; o >>= 1) s += __shfl_xor(s, o, 16);
    float r = v - m - __logf(s);
    if (isBf16) ((__hip_bfloat16*)out)[(size_t)d * D_OUT + j] = __float2bfloat16(r);
    else        ((float*)out)[(size_t)d * D_OUT + j] = r;
}

extern "C" void kernel_launch(void* const* d_in, const int* in_sizes, int n_in,
                              void* d_out, int out_size, void* d_ws, size_t ws_size,
                              hipStream_t stream)
{
    const unsigned* xraw  = (const unsigned*)d_in[0];
    const int*      ei    = (const int*)d_in[1];
    const unsigned* w1raw = (const unsigned*)d_in[2];
    const unsigned* b1raw = (const unsigned*)d_in[3];
    const unsigned* w2raw = (const unsigned*)d_in[4];
    const unsigned* b2raw = (const unsigned*)d_in[5];

    const int n  = in_sizes[0] / D_IN;   // 100000
    const int ne = in_sizes[1] / 2;      // 1600000
    const int B  = (n + ((1 << WSHIFT) - 1)) >> WSHIFT;   // 98 buckets

    // ws layout (4B words):
    // flags[64] | gcur[128] | dinv[nAl] | off[nAl+64] | csr[neAl] | gbuf[B*BCAP]
    //   | h1b[n*64 bf16] | actb[n*64 bf16] | h2b[n*16 bf16]
    size_t nAl  = ((size_t)n + 255) & ~(size_t)255;
    size_t neAl = ((size_t)ne + 255) & ~(size_t)255;
    int*            flags = (int*)d_ws;
    unsigned*       gcur  = (unsigned*)d_ws + 64;
    float*          dinv  = (float*)(gcur + 128);
    unsigned*       off   = (unsigned*)(dinv + nAl);
    int*            csr   = (int*)(off + nAl + 64);
    unsigned*       gbuf  = (unsigned*)(csr + neAl);
    unsigned short* h1b   = (unsigned short*)(gbuf + (size_t)MAXB * BCAP);
    unsigned short* actb  = h1b + (size_t)n * D_HID;
    unsigned short* h2b   = actb + (size_t)n * D_HID;

    const int nchunk = (ne + CHUNK - 1) / CHUNK;

    k_detect    <<<1, 128, 0, stream>>>(xraw, ei, flags, gcur);
    k_bucketize <<<nchunk, 256, 0, stream>>>(ei, flags, gcur, gbuf, ne, B);
    k_build     <<<B, 256, 0, stream>>>(gbuf, gcur, off, dinv, csr, n, B);

    k_linear1   <<<768, 256, 0, stream>>>(xraw, w1raw, flags, h1b, n);
    k_aggA      <<<(n + 3) / 4, 256, 0, stream>>>(off, csr, dinv, h1b, b1raw, flags, actb, n);
    k_linear2   <<<768, 256, 0, stream>>>(actb, w2raw, flags, h2b, n);
    k_aggB      <<<(n + 15) / 16, 256, 0, stream>>>(off, csr, dinv, h2b, b2raw, flags, d_out, n);
}